// Round 10
// baseline (190.085 us; speedup 1.0000x reference)
//
#include <hip/hip_runtime.h>

typedef float f4 __attribute__((ext_vector_type(4)));

#define HID 2048
#define DFF 5461
#define NE  8

// ws (d_ws) float offsets
#define WS_TS 0           // 64 chunks * 8 experts exp-sum partials
#define WS_EO 1024        // 8*2048

// d_out used as large scratch (float offsets); fully overwritten by k_comb.
// Audit: TP [0, 1,048,576) | MP [1,048,576, 1,747,584) | EP [1,747,584, 2,796,160)
#define SC_TP 0
#define SC_MP 1048576
#define SC_EP 1747584

// ---- t partials (unnormalized exp weights; s partials in double -> d_ws):
// grid (8 col-blocks of 64 f4, 64 row-chunks of 128), block 256
__global__ __launch_bounds__(256) void k_tpart(const float* __restrict__ x,
                                               const float* __restrict__ rw,
                                               float* __restrict__ sc,
                                               float* __restrict__ wsb) {
  __shared__ f4 dv4[64][2];
  __shared__ f4 red[3][NE][64];
  int tid = threadIdx.x;
  int rc = blockIdx.y;
  int col = tid & 63, rg = tid >> 6;
  int c4 = blockIdx.x * 64 + col;
  const f4* x4 = (const f4*)x;
  f4 acc[NE];
#pragma unroll
  for (int e = 0; e < NE; e++) acc[e] = (f4){0.f, 0.f, 0.f, 0.f};
  double spart = 0.0;
  for (int sub = 0; sub < 2; sub++) {
    int b0 = rc * 128 + sub * 64;
    if (tid < 128) {
      int row = tid >> 1, half = tid & 1;
      const float* rp = rw + (size_t)(b0 + row) * NE + half * 4;
      f4 d;
      d.x = __expf(rp[0]);
      d.y = __expf(rp[1]);
      d.z = __expf(rp[2]);
      d.w = __expf(rp[3]);
      dv4[row][half] = d;
    }
    __syncthreads();
    if (blockIdx.x == 0 && tid < NE) {
      const float* dp = (const float*)dv4;
      for (int row = 0; row < 64; row++) spart += (double)dp[row * 8 + tid];
    }
#pragma unroll 8
    for (int r = 0; r < 16; r++) {
      int row = rg * 16 + r;
      f4 xv = __builtin_nontemporal_load(&x4[(size_t)(b0 + row) * 512 + c4]);
      f4 dlo = dv4[row][0], dhi = dv4[row][1];
      acc[0] += dlo.x * xv;
      acc[1] += dlo.y * xv;
      acc[2] += dlo.z * xv;
      acc[3] += dlo.w * xv;
      acc[4] += dhi.x * xv;
      acc[5] += dhi.y * xv;
      acc[6] += dhi.z * xv;
      acc[7] += dhi.w * xv;
    }
    __syncthreads();
  }
  if (blockIdx.x == 0 && tid < NE) wsb[WS_TS + rc * NE + tid] = (float)spart;
  if (rg) {
#pragma unroll
    for (int e = 0; e < NE; e++) red[rg - 1][e][col] = acc[e];
  }
  __syncthreads();
  if (!rg) {
    f4* o4 = (f4*)(sc + SC_TP);
#pragma unroll
    for (int e = 0; e < NE; e++) {
      f4 a = acc[e] + red[0][e][col] + red[1][e][col] + red[2][e][col];
      o4[(size_t)(rc * NE + e) * 512 + c4] = a;
    }
  }
}

// ---- up-proj (fused t reduce + inv_s scale in prologue):
// grid (16 f-spans of 342, 16 h-chunks of 128, 4 groups) = 1024 blocks
__global__ __launch_bounds__(256) void k_midpart(const float* __restrict__ up_w,
                                                 const float* __restrict__ sc_tp,
                                                 const float* __restrict__ wsb,
                                                 float* __restrict__ sc) {
  int fb = blockIdx.x, hc = blockIdx.y, g = blockIdx.z;
  int tid = threadIdx.x;
  __shared__ float t0[128], t1[128];
  __shared__ float s01[2];
  int h0 = hc * 128;
  // inv_s for experts 2g, 2g+1 (double, deterministic)
  if (tid < 2) {
    double s = 0.0;
    for (int ch = 0; ch < 64; ch++)
      s += (double)wsb[WS_TS + ch * NE + 2 * g + tid];
    s01[tid] = (float)(1.0 / s);
  }
  // t reduce over 64 chunks (double inner)
  {
    int half = tid >> 7, h = tid & 127;
    double a = 0.0;
    for (int ch = 0; ch < 64; ch++)
      a += (double)sc_tp[SC_TP + (size_t)(ch * NE + 2 * g + half) * HID + h0 + h];
    if (half == 0) t0[h] = (float)a;
    else t1[h] = (float)a;
  }
  __syncthreads();
  if (tid < 128) t0[tid] *= s01[0];
  else t1[tid - 128] *= s01[1];
  __syncthreads();
  int fstart = fb * 342;
  int fend = min(fstart + 342, DFF);
  int fA = fstart + tid;
  int fB = fA + 256;
  bool hasA = fA < fend, hasB = fB < fend;
  const float* wp = up_w + ((size_t)g * HID + h0) * DFF;
  float a0 = 0.f, a1 = 0.f, bb0 = 0.f, bb1 = 0.f;
#pragma unroll 8
  for (int h = 0; h < 128; h++) {
    float wA = hasA ? __builtin_nontemporal_load(wp + (size_t)h * DFF + fA) : 0.f;
    float wB = hasB ? __builtin_nontemporal_load(wp + (size_t)h * DFF + fB) : 0.f;
    a0 += t0[h] * wA;
    a1 += t1[h] * wA;
    bb0 += t0[h] * wB;
    bb1 += t1[h] * wB;
  }
  float* mp = sc + SC_MP + (size_t)hc * NE * DFF;
  if (hasA) {
    mp[(size_t)(2 * g) * DFF + fA] = a0;
    mp[(size_t)(2 * g + 1) * DFF + fA] = a1;
  }
  if (hasB) {
    mp[(size_t)(2 * g) * DFF + fB] = bb0;
    mp[(size_t)(2 * g + 1) * DFF + fB] = bb1;
  }
}

// ---- down-proj: grid (2 h-halves, 64 f-chunks of 86, 8 experts) = 1024 blocks
// fused mid reduce (double) + bias + silu, wave-local; 8-row preload pipeline
__global__ __launch_bounds__(256) void k_eopart(const float* __restrict__ down_w,
                                                const float* __restrict__ up_b,
                                                const float* __restrict__ sc_mp,
                                                float* __restrict__ sc) {
  int hb = blockIdx.x, fc = blockIdx.y, e = blockIdx.z;
  int tid = threadIdx.x;
  int f0 = fc * 86;
  int nf = min(86, DFF - f0);  // 86, or 43 for fc == 63
  const f4* base4 = (const f4*)down_w + ((size_t)e * DFF + f0) * 512 + hb * 256 + tid;
  f4 w[8];
#pragma unroll
  for (int j = 0; j < 8; j++)
    w[j] = __builtin_nontemporal_load(&base4[(size_t)j * 512]);
  __shared__ float ml[4][86];
  int lane = tid & 63, wv = tid >> 6;
  for (int f = lane; f < nf; f += 64) {
    double a = (double)up_b[(size_t)(e >> 1) * DFF + f0 + f];
#pragma unroll 4
    for (int k = 0; k < 16; k++)
      a += (double)sc_mp[SC_MP + (size_t)(k * NE + e) * DFF + f0 + f];
    float af = (float)a;
    ml[wv][f] = af / (1.f + __expf(-af));
  }
  f4 acc = (f4){0.f, 0.f, 0.f, 0.f};
  int nfull = nf >> 3;   // 10 or 5
  int ntail = nf & 7;    // 6 or 3
  for (int blk = 0; blk < nfull; blk++) {
#pragma unroll
    for (int j = 0; j < 8; j++) {
      int cur = blk * 8 + j;
      f4 c = w[j];
      int nxt = cur + 8;
      if (nxt < nf) w[j] = __builtin_nontemporal_load(&base4[(size_t)nxt * 512]);
      acc += ml[wv][cur] * c;
    }
  }
#pragma unroll
  for (int j = 0; j < 8; j++)
    if (j < ntail) acc += ml[wv][nfull * 8 + j] * w[j];
  ((f4*)(sc + SC_EP))[(size_t)(fc * NE + e) * 512 + hb * 256 + tid] = acc;
}

// ---- eo reduce + bias: 512 blocks, 32 outputs each (double inner)
__global__ __launch_bounds__(256) void k_eored(const float* __restrict__ sc,
                                               const float* __restrict__ down_b,
                                               float* __restrict__ wsb) {
  __shared__ float red[8][32];
  int tid = threadIdx.x;
  int o = tid & 31, grp = tid >> 5;
  int i = blockIdx.x * 32 + o;
  double a = 0.0;
  for (int fc = grp; fc < 64; fc += 8)
    a += (double)sc[SC_EP + (size_t)fc * (NE * HID) + i];
  red[grp][o] = (float)a;
  __syncthreads();
  if (tid < 32) {
    int ii = blockIdx.x * 32 + tid;
    float s = down_b[ii];
#pragma unroll
    for (int g = 0; g < 8; g++) s += red[g][tid];
    wsb[WS_EO + ii] = s;
  }
}

// ---- combine: 16 tokens/block, eo in regs, nt stores; inv_s from ws partials
__global__ __launch_bounds__(256) void k_comb(const float* __restrict__ rw,
                                              const float* __restrict__ wsb,
                                              float* __restrict__ y) {
  int tid = threadIdx.x;
  int b0 = blockIdx.x * 16;
  __shared__ float dvl[16][NE];
  __shared__ float sinv[NE];
  const f4* eo4 = (const f4*)(wsb + WS_EO);
  f4 ea[NE], eb[NE];
#pragma unroll
  for (int e = 0; e < NE; e++) {
    ea[e] = eo4[e * 512 + tid];
    eb[e] = eo4[e * 512 + 256 + tid];
  }
  if (tid < NE) {
    double s = 0.0;  // deterministic: same order in every block
    for (int ch = 0; ch < 64; ch++) s += (double)wsb[WS_TS + ch * NE + tid];
    sinv[tid] = (float)(1.0 / s);
  }
  __syncthreads();
  if (tid < 128) {
    int tok = tid >> 3, e = tid & 7;
    dvl[tok][e] = __expf(rw[(size_t)(b0 + tok) * NE + e]) * sinv[e];
  }
  __syncthreads();
  f4* y4 = (f4*)y;
#pragma unroll 4
  for (int t = 0; t < 16; t++) {
    f4 o0 = (f4){0.f, 0.f, 0.f, 0.f};
    f4 o1 = (f4){0.f, 0.f, 0.f, 0.f};
#pragma unroll
    for (int e = 0; e < NE; e++) {
      float d = dvl[t][e];
      o0 += d * ea[e];
      o1 += d * eb[e];
    }
    __builtin_nontemporal_store(o0, &y4[(size_t)(b0 + t) * 512 + tid]);
    __builtin_nontemporal_store(o1, &y4[(size_t)(b0 + t) * 512 + 256 + tid]);
  }
}

extern "C" void kernel_launch(void* const* d_in, const int* in_sizes, int n_in,
                              void* d_out, int out_size, void* d_ws, size_t ws_size,
                              hipStream_t stream) {
  const float* x      = (const float*)d_in[0];
  const float* rw     = (const float*)d_in[1];
  const float* up_w   = (const float*)d_in[2];
  const float* up_b   = (const float*)d_in[3];
  const float* down_w = (const float*)d_in[4];
  const float* down_b = (const float*)d_in[5];
  float* y   = (float*)d_out;
  float* wsb = (float*)d_ws;
  float* sc  = y;  // large scratch in d_out; k_comb overwrites all of it

  hipLaunchKernelGGL(k_tpart, dim3(8, 64), dim3(256), 0, stream, x, rw, sc, wsb);
  hipLaunchKernelGGL(k_midpart, dim3(16, 16, 4), dim3(256), 0, stream, up_w, sc, wsb, sc);
  hipLaunchKernelGGL(k_eopart, dim3(2, 64, 8), dim3(256), 0, stream, down_w, up_b, sc, sc);
  hipLaunchKernelGGL(k_eored, dim3(512), dim3(256), 0, stream, sc, down_b, wsb);
  hipLaunchKernelGGL(k_comb, dim3(512), dim3(256), 0, stream, rw, wsb, y);
}

// Round 11
// 133.388 us; speedup vs baseline: 1.4250x; 1.4250x over previous
//
#include <hip/hip_runtime.h>

typedef float f4 __attribute__((ext_vector_type(4)));

#define HID 2048
#define DFF 5461
#define NE  8

// ws float offsets
#define WS_IS 0           // inv_s[8]
#define WS_T  64          // 8*2048 (normalized t)
#define WS_EO 16448       // 8*2048

// d_out used as large scratch (float offsets); fully overwritten by k_comb.
// Audit: TP [0, 1,048,576) | TS [1,048,576, 1,049,088) | MP [1,049,600, 1,748,608)
//        EP [1,748,736, 3,829,504) | MID [3,829,760, 3,873,448)  -- disjoint
#define SC_TP  0
#define SC_TS  1048576
#define SC_MP  1049600
#define SC_EP  1748736
#define SC_MID 3829760

// ---- t partials (unnormalized exp weights; s partials in double):
// grid (8 col-blocks of 64 f4, 64 row-chunks of 128), block 256
__global__ __launch_bounds__(256) void k_tpart(const float* __restrict__ x,
                                               const float* __restrict__ rw,
                                               float* __restrict__ sc) {
  __shared__ f4 dv4[64][2];
  __shared__ f4 red[3][NE][64];
  int tid = threadIdx.x;
  int rc = blockIdx.y;
  int col = tid & 63, rg = tid >> 6;
  int c4 = blockIdx.x * 64 + col;
  const f4* x4 = (const f4*)x;
  f4 acc[NE];
#pragma unroll
  for (int e = 0; e < NE; e++) acc[e] = (f4){0.f, 0.f, 0.f, 0.f};
  double spart = 0.0;
  for (int sub = 0; sub < 2; sub++) {
    int b0 = rc * 128 + sub * 64;
    if (tid < 128) {
      int row = tid >> 1, half = tid & 1;
      const float* rp = rw + (size_t)(b0 + row) * NE + half * 4;
      f4 d;
      d.x = __expf(rp[0]);
      d.y = __expf(rp[1]);
      d.z = __expf(rp[2]);
      d.w = __expf(rp[3]);
      dv4[row][half] = d;
    }
    __syncthreads();
    // exp-sum chunk partials (only col-block 0; threads 0..7) -- DOUBLE accum
    if (blockIdx.x == 0 && tid < NE) {
      const float* dp = (const float*)dv4;
      for (int row = 0; row < 64; row++) spart += (double)dp[row * 8 + tid];
    }
#pragma unroll 4
    for (int r = 0; r < 16; r++) {
      int row = rg * 16 + r;
      f4 xv = __builtin_nontemporal_load(&x4[(size_t)(b0 + row) * 512 + c4]);
      f4 dlo = dv4[row][0], dhi = dv4[row][1];
      acc[0] += dlo.x * xv;
      acc[1] += dlo.y * xv;
      acc[2] += dlo.z * xv;
      acc[3] += dlo.w * xv;
      acc[4] += dhi.x * xv;
      acc[5] += dhi.y * xv;
      acc[6] += dhi.z * xv;
      acc[7] += dhi.w * xv;
    }
    __syncthreads();
  }
  if (blockIdx.x == 0 && tid < NE) sc[SC_TS + rc * NE + tid] = (float)spart;
  if (rg) {
#pragma unroll
    for (int e = 0; e < NE; e++) red[rg - 1][e][col] = acc[e];
  }
  __syncthreads();
  if (!rg) {
    f4* o4 = (f4*)(sc + SC_TP);
#pragma unroll
    for (int e = 0; e < NE; e++) {
      f4 a = acc[e] + red[0][e][col] + red[1][e][col] + red[2][e][col];
      o4[(size_t)(rc * NE + e) * 512 + c4] = a;
    }
  }
}

// ---- t reduce + 1/s fold: 512 blocks, 32 outputs each, 8 chunk-groups of 8
__global__ __launch_bounds__(256) void k_tred(const float* __restrict__ sc,
                                              float* __restrict__ ws) {
  __shared__ float red[8][32];
  __shared__ float sinv[NE];
  int tid = threadIdx.x;
  if (tid < NE) {
    double s = 0.0;  // DOUBLE accum over 64 chunk partials
    for (int ch = 0; ch < 64; ch++) s += (double)sc[SC_TS + ch * NE + tid];
    float inv = (float)(1.0 / s);
    sinv[tid] = inv;
    if (blockIdx.x == 0) ws[WS_IS + tid] = inv;
  }
  int o = tid & 31, grp = tid >> 5;
  int i = blockIdx.x * 32 + o;
  double a = 0.0;
#pragma unroll 4
  for (int k = 0; k < 8; k++)
    a += (double)sc[SC_TP + (size_t)(grp * 8 + k) * (NE * HID) + i];
  red[grp][o] = (float)a;
  __syncthreads();
  if (tid < 32) {
    int ii = blockIdx.x * 32 + tid;
    float s = 0.f;
#pragma unroll
    for (int g = 0; g < 8; g++) s += red[g][tid];
    ws[WS_T + ii] = s * sinv[ii >> 11];
  }
}

// ---- up-proj partials: grid (11 f-spans of 512, 16 h-chunks of 128, 4 groups)
__global__ __launch_bounds__(256) void k_midpart(const float* __restrict__ up_w,
                                                 const float* __restrict__ ws,
                                                 float* __restrict__ sc) {
  int fb = blockIdx.x, hc = blockIdx.y, g = blockIdx.z;
  int tid = threadIdx.x;
  __shared__ float t0[128], t1[128];
  int h0 = hc * 128;
  if (tid < 128) t0[tid] = ws[WS_T + (2 * g) * HID + h0 + tid];
  else t1[tid - 128] = ws[WS_T + (2 * g + 1) * HID + h0 + tid - 128];
  __syncthreads();
  int fA = fb * 512 + tid;  // < 5376 always
  int fB = fA + 256;
  bool hasB = fB < DFF;
  const float* wp = up_w + ((size_t)g * HID + h0) * DFF;
  float a0 = 0.f, a1 = 0.f, bb0 = 0.f, bb1 = 0.f;
#pragma unroll 8
  for (int h = 0; h < 128; h++) {
    float wA = __builtin_nontemporal_load(wp + (size_t)h * DFF + fA);
    float wB = hasB ? __builtin_nontemporal_load(wp + (size_t)h * DFF + fB) : 0.f;
    a0 += t0[h] * wA;
    a1 += t1[h] * wA;
    bb0 += t0[h] * wB;
    bb1 += t1[h] * wB;
  }
  float* mp = sc + SC_MP + (size_t)hc * NE * DFF;
  mp[(size_t)(2 * g) * DFF + fA] = a0;
  mp[(size_t)(2 * g + 1) * DFF + fA] = a1;
  if (hasB) {
    mp[(size_t)(2 * g) * DFF + fB] = bb0;
    mp[(size_t)(2 * g + 1) * DFF + fB] = bb1;
  }
}

// ---- mid finalize: reduce 16 h-chunks + bias + silu, once per (e,f).
// grid (22 f-blocks, 8 experts), block 256; coalesced reads/writes
__global__ __launch_bounds__(256) void k_midred(const float* __restrict__ sc_mp,
                                                const float* __restrict__ up_b,
                                                float* __restrict__ sc) {
  int f = blockIdx.x * 256 + threadIdx.x;
  int e = blockIdx.y;
  if (f >= DFF) return;
  double a = (double)up_b[(size_t)(e >> 1) * DFF + f];
#pragma unroll 4
  for (int k = 0; k < 16; k++)
    a += (double)sc_mp[SC_MP + (size_t)(k * NE + e) * DFF + f];
  float af = (float)a;
  sc[SC_MID + (size_t)e * DFF + f] = af / (1.f + __expf(-af));
}

// ---- down-proj: grid (2 h-halves, 127 f-chunks of 43, 8 experts), block 256
// mid read is a single coalesced 43-float load; 8-row preload pipeline
__global__ __launch_bounds__(256) void k_eopart(const float* __restrict__ down_w,
                                                const float* __restrict__ sc_mid,
                                                float* __restrict__ sc) {
  int hb = blockIdx.x, fc = blockIdx.y, e = blockIdx.z;
  int tid = threadIdx.x;
  int f0 = fc * 43;
  const f4* base4 = (const f4*)down_w + ((size_t)e * DFF + f0) * 512 + hb * 256 + tid;
  // preload first 8 rows (in flight across the prologue)
  f4 w[8];
#pragma unroll
  for (int j = 0; j < 8; j++)
    w[j] = __builtin_nontemporal_load(&base4[(size_t)j * 512]);
  __shared__ float ml[4][43];
  int lane = tid & 63, wv = tid >> 6;
  if (lane < 43) ml[wv][lane] = sc_mid[SC_MID + (size_t)e * DFF + f0 + lane];
  f4 acc = (f4){0.f, 0.f, 0.f, 0.f};
  for (int blk = 0; blk < 5; blk++) {
#pragma unroll
    for (int j = 0; j < 8; j++) {
      int cur = blk * 8 + j;
      f4 c = w[j];
      int nxt = cur + 8;
      if (nxt < 43) w[j] = __builtin_nontemporal_load(&base4[(size_t)nxt * 512]);
      acc += ml[wv][cur] * c;
    }
  }
#pragma unroll
  for (int j = 0; j < 3; j++) acc += ml[wv][40 + j] * w[j];
  ((f4*)(sc + SC_EP))[(size_t)(fc * NE + e) * 512 + hb * 256 + tid] = acc;
}

// ---- eo reduce + bias: 512 blocks, 32 outputs each (double inner)
__global__ __launch_bounds__(256) void k_eored(const float* __restrict__ sc,
                                               const float* __restrict__ down_b,
                                               float* __restrict__ ws) {
  __shared__ float red[8][32];
  int tid = threadIdx.x;
  int o = tid & 31, grp = tid >> 5;
  int i = blockIdx.x * 32 + o;
  double a = 0.0;
  for (int fc = grp; fc < 127; fc += 8)
    a += (double)sc[SC_EP + (size_t)fc * (NE * HID) + i];
  red[grp][o] = (float)a;
  __syncthreads();
  if (tid < 32) {
    int ii = blockIdx.x * 32 + tid;
    float s = down_b[ii];
#pragma unroll
    for (int g = 0; g < 8; g++) s += red[g][tid];
    ws[WS_EO + ii] = s;
  }
}

// ---- combine: 16 tokens/block, eo in regs, nt stores
__global__ __launch_bounds__(256) void k_comb(const float* __restrict__ rw,
                                              const float* __restrict__ ws,
                                              float* __restrict__ y) {
  int tid = threadIdx.x;
  int b0 = blockIdx.x * 16;
  __shared__ float dvl[16][NE];
  if (tid < 128) {
    int tok = tid >> 3, e = tid & 7;
    dvl[tok][e] = __expf(rw[(size_t)(b0 + tok) * NE + e]) * ws[WS_IS + e];
  }
  __syncthreads();
  const f4* eo4 = (const f4*)(ws + WS_EO);
  f4 ea[NE], eb[NE];
#pragma unroll
  for (int e = 0; e < NE; e++) {
    ea[e] = eo4[e * 512 + tid];
    eb[e] = eo4[e * 512 + 256 + tid];
  }
  f4* y4 = (f4*)y;
#pragma unroll 4
  for (int t = 0; t < 16; t++) {
    f4 o0 = (f4){0.f, 0.f, 0.f, 0.f};
    f4 o1 = (f4){0.f, 0.f, 0.f, 0.f};
#pragma unroll
    for (int e = 0; e < NE; e++) {
      float d = dvl[t][e];
      o0 += d * ea[e];
      o1 += d * eb[e];
    }
    __builtin_nontemporal_store(o0, &y4[(size_t)(b0 + t) * 512 + tid]);
    __builtin_nontemporal_store(o1, &y4[(size_t)(b0 + t) * 512 + 256 + tid]);
  }
}

extern "C" void kernel_launch(void* const* d_in, const int* in_sizes, int n_in,
                              void* d_out, int out_size, void* d_ws, size_t ws_size,
                              hipStream_t stream) {
  const float* x      = (const float*)d_in[0];
  const float* rw     = (const float*)d_in[1];
  const float* up_w   = (const float*)d_in[2];
  const float* up_b   = (const float*)d_in[3];
  const float* down_w = (const float*)d_in[4];
  const float* down_b = (const float*)d_in[5];
  float* y  = (float*)d_out;
  float* ws = (float*)d_ws;
  float* sc = y;  // large scratch in d_out; k_comb overwrites all of it

  hipLaunchKernelGGL(k_tpart, dim3(8, 64), dim3(256), 0, stream, x, rw, sc);
  hipLaunchKernelGGL(k_tred, dim3(512), dim3(256), 0, stream, sc, ws);
  hipLaunchKernelGGL(k_midpart, dim3(11, 16, 4), dim3(256), 0, stream, up_w, ws, sc);
  hipLaunchKernelGGL(k_midred, dim3(22, 8), dim3(256), 0, stream, sc, up_b, sc);
  hipLaunchKernelGGL(k_eopart, dim3(2, 127, 8), dim3(256), 0, stream, down_w, sc, sc);
  hipLaunchKernelGGL(k_eored, dim3(512), dim3(256), 0, stream, sc, down_b, ws);
  hipLaunchKernelGGL(k_comb, dim3(512), dim3(256), 0, stream, rw, ws, y);
}